// Round 8
// baseline (1827.043 us; speedup 1.0000x reference)
//
#include <hip/hip_runtime.h>
#include <hip/hip_bf16.h>

typedef __attribute__((ext_vector_type(8))) short bf16x8;
typedef __attribute__((ext_vector_type(4))) float f32x4;

#define L_SEQ 128
#define BATCH 64
#define HID   1024
#define GATES 4096
#define NWG   64    // scan workgroups (regular launch; 64 <= 256 CUs co-resident)
#define UPW   16    // hidden units per scan WG
#define SLOTB (BATCH * HID * 2)            // bytes per h time-slot (128 KB)
#define CAN32 0x7FC17FC1u                  // canary dword (bf16 high byte 0x7F
                                           // impossible for |h|<1 data)
#define CAN64 0x7FC17FC17FC17FC1ull

__device__ inline short f2bf_s(float f) {
  __hip_bfloat16 h = __float2bfloat16(f);
  union { __hip_bfloat16 hh; short s; } u; u.hh = h; return u.s;
}
__device__ inline float bf2f_u(unsigned short s) {
  union { unsigned u; float f; } u; u.u = ((unsigned)s) << 16; return u.f;
}
__device__ inline float sigm(float x) { return 1.f / (1.f + __expf(-x)); }
__device__ inline float tanh_f(float x) {
  x = fminf(x, 15.f);                 // avoid inf/inf NaN
  float e = __expf(2.f * x);
  return (e - 1.f) / (e + 1.f);
}
// reject if EITHER 4B half is canary -> torn 8B stores respin, never accepted
__device__ inline bool is_can(unsigned long long q) {
  return ((unsigned)q == CAN32) | ((unsigned)(q >> 32) == CAN32);
}

// ---------------- init: h_all[0] <- hidden (chunk-16 layout), canary slots ---
// ALL h_all writes are system-scope UC stores: consumers read h_all with
// system-scope UC loads, so init data must be at the coherence point, not in
// an XCD's L2 awaiting writeback.
// chunk-16 layout per slot: [c][b][u'16]  (c = unit>>4, u' = unit&15).
__global__ void k_init(const float* __restrict__ hidden, const float* __restrict__ x,
                       const float* __restrict__ bih, const float* __restrict__ bhh,
                       __hip_bfloat16* __restrict__ h_all0, __hip_bfloat16* __restrict__ x_bf,
                       float* __restrict__ bias2) {
  int gid = blockIdx.x * 256 + threadIdx.x;            // 65536 threads
  unsigned long long* hw = (unsigned long long*)h_all0;
  if (gid < BATCH * HID / 4) {                         // 16384 u64s of slot 0
    int c = gid >> 8, wi = gid & 255, b = wi >> 2, xq = wi & 3;
    float4 f = *(const float4*)(hidden + (size_t)b * HID + c * 16 + xq * 4);
    union { unsigned long long u; unsigned short s[4]; } p;
    p.s[0] = (unsigned short)f2bf_s(f.x); p.s[1] = (unsigned short)f2bf_s(f.y);
    p.s[2] = (unsigned short)f2bf_s(f.z); p.s[3] = (unsigned short)f2bf_s(f.w);
    __hip_atomic_store(&hw[gid], p.u, __ATOMIC_RELAXED, __HIP_MEMORY_SCOPE_SYSTEM);
  }
  if (gid < BATCH * 512) x_bf[gid]  = __float2bfloat16(x[gid]);
  if (gid < GATES)       bias2[gid] = bih[gid] + bhh[gid];
  // canary-fill slots 1..128 (16 MB) via UC stores
  unsigned long long* cw = hw + (size_t)BATCH * HID / 4;
  for (size_t i = gid; i < (size_t)L_SEQ * BATCH * HID / 4; i += 65536)
    __hip_atomic_store(&cw[i], CAN64, __ATOMIC_RELAXED, __HIP_MEMORY_SCOPE_SYSTEM);
}

// ---------------- split W_ih into bf16 Wx (4096x512) and Wa (4096x512) -------
__global__ void k_wsplit(const float* __restrict__ Wih,
                         __hip_bfloat16* __restrict__ Wx, __hip_bfloat16* __restrict__ Wa) {
  int e = blockIdx.x * 256 + threadIdx.x;              // 4096*128
  int g = e >> 7;
  int ko = (e & 127) << 3;
  const float* src = Wih + (size_t)g * 1024 + ko;
  float4 f0 = *(const float4*)(src);
  float4 f1 = *(const float4*)(src + 4);
  union { bf16x8 v; short s[8]; } o;
  o.s[0]=f2bf_s(f0.x); o.s[1]=f2bf_s(f0.y); o.s[2]=f2bf_s(f0.z); o.s[3]=f2bf_s(f0.w);
  o.s[4]=f2bf_s(f1.x); o.s[5]=f2bf_s(f1.y); o.s[6]=f2bf_s(f1.z); o.s[7]=f2bf_s(f1.w);
  if (ko < 512) *(bf16x8*)(Wx + (size_t)g * 512 + ko)        = o.v;
  else          *(bf16x8*)(Wa + (size_t)g * 512 + (ko - 512)) = o.v;
}

// ---------------- act[l*64+b][512] = rule_emb[r]*v + tok_emb[t]*v (bf16) -----
__global__ void k_act(const int* __restrict__ pa, const float* __restrict__ remb,
                      const float* __restrict__ temb, __hip_bfloat16* __restrict__ act) {
  int row = blockIdx.x;                                // 8192 = l*64+b
  int tid = threadIdx.x;                               // 64
  int r  = pa[row * 3 + 0];
  int tk = pa[row * 3 + 1];
  float sr = (r  != -1) ? 1.f : 0.f; int ri = (r  != -1) ? r  : 0;
  float st = (tk != -1) ? 1.f : 0.f; int ti = (tk != -1) ? tk : 0;
  const float4* rr = (const float4*)(remb + (size_t)ri * 512);
  const float4* tr = (const float4*)(temb + (size_t)ti * 512);
  float4 a = rr[tid * 2], b4 = rr[tid * 2 + 1];
  float4 c4 = tr[tid * 2], d4 = tr[tid * 2 + 1];
  union { bf16x8 v; short s[8]; } o;
  o.s[0]=f2bf_s(sr*a.x + st*c4.x);  o.s[1]=f2bf_s(sr*a.y + st*c4.y);
  o.s[2]=f2bf_s(sr*a.z + st*c4.z);  o.s[3]=f2bf_s(sr*a.w + st*c4.w);
  o.s[4]=f2bf_s(sr*b4.x + st*d4.x); o.s[5]=f2bf_s(sr*b4.y + st*d4.y);
  o.s[6]=f2bf_s(sr*b4.z + st*d4.z); o.s[7]=f2bf_s(sr*b4.w + st*d4.w);
  *(bf16x8*)(act + (size_t)row * 512 + tid * 8) = o.v;
}

// ---------------- bf16 MFMA GEMM: C[m,n] = A[m,:]·B[n,:] + addend ------------
// MODE 0: Cf (fp32) = A@B^T + bias2[n]           (y0: M=64)
// MODE 1: Cb (bf16) = A@B^T + y0[m&63][n]        (xg: M=8192)
template<int MODE>
__global__ __launch_bounds__(256) void k_gemm(
    const __hip_bfloat16* __restrict__ A, const __hip_bfloat16* __restrict__ B,
    const float* __restrict__ addend, float* __restrict__ Cf,
    __hip_bfloat16* __restrict__ Cb, int M) {
  __shared__ __hip_bfloat16 At[128][72];   // +8 pad -> 2-way (free) LDS access
  __shared__ __hip_bfloat16 Bt[128][72];
  const int tid = threadIdx.x;
  const int m0 = blockIdx.y * 128, n0 = blockIdx.x * 128;
  const int w = tid >> 6, lane = tid & 63;
  const int wm = (w >> 1) * 64, wn = (w & 1) * 64;
  const int lm = lane & 15, quad = lane >> 4;
  const int srow = tid >> 1, shalf = (tid & 1) * 32;
  f32x4 acc[4][4] = {};
  for (int k0 = 0; k0 < 512; k0 += 64) {
    int arow = m0 + srow;
    if (MODE == 0 && arow >= M) arow = M - 1;          // clamp (stores guarded)
    const bf16x8* ag = (const bf16x8*)(A + (size_t)arow * 512 + k0 + shalf);
    const bf16x8* bg = (const bf16x8*)(B + (size_t)(n0 + srow) * 512 + k0 + shalf);
    bf16x8 av[4], bv[4];
#pragma unroll
    for (int q = 0; q < 4; ++q) { av[q] = ag[q]; bv[q] = bg[q]; }
    __syncthreads();
#pragma unroll
    for (int q = 0; q < 4; ++q) {
      *(bf16x8*)(&At[srow][shalf + q * 8]) = av[q];
      *(bf16x8*)(&Bt[srow][shalf + q * 8]) = bv[q];
    }
    __syncthreads();
#pragma unroll
    for (int ks = 0; ks < 2; ++ks) {
      bf16x8 af[4], bf[4];
#pragma unroll
      for (int i = 0; i < 4; ++i) {
        af[i] = *(const bf16x8*)(&At[wm + i * 16 + lm][ks * 32 + quad * 8]);
        bf[i] = *(const bf16x8*)(&Bt[wn + i * 16 + lm][ks * 32 + quad * 8]);
      }
#pragma unroll
      for (int i = 0; i < 4; ++i)
#pragma unroll
        for (int j = 0; j < 4; ++j)
          acc[i][j] = __builtin_amdgcn_mfma_f32_16x16x32_bf16(af[i], bf[j], acc[i][j], 0, 0, 0);
    }
  }
  // C/D layout: col = lane&15, row = quad*4 + reg  (m89-verified)
#pragma unroll
  for (int i = 0; i < 4; ++i) {
    int mrow = m0 + wm + i * 16 + quad * 4;
#pragma unroll
    for (int j = 0; j < 4; ++j) {
      int ncol = n0 + wn + j * 16 + lm;
#pragma unroll
      for (int r = 0; r < 4; ++r) {
        int m = mrow + r;
        if (MODE == 0) {
          if (m < M) Cf[(size_t)m * GATES + ncol] = acc[i][j][r] + addend[ncol];
        } else {
          float v = acc[i][j][r] + addend[(size_t)(m & 63) * GATES + ncol];
          Cb[(size_t)m * GATES + ncol] = __float2bfloat16(v);
        }
      }
    }
  }
}

// ---------------- persistent LSTM scan (barrier-free, canary-synced) ---------
// v13 = v11 EXACTLY, but launched as a REGULAR kernel (not cooperative).
// v9-v11 produced bit-identical untouched output (absmax 0.879 = all-zero
// out_hs; a real race or budget exhaustion would have produced NaNs since the
// canary is bf16 NaN and propagates) -> k_scan never executed; prime suspect
// is a silently-swallowed cooperative-launch rejection. The canary protocol
// needs NO grid.sync, and 64 blocks <= 256 CUs are co-resident under a
// regular launch on an idle device. Protocol (unchanged from v11):
// one system-scope hop per step; producers fire relaxed UC stores and move
// on; consumers validate each 16B fragment (per-4B canary check, torn-store
// safe) right before its MFMAs; spin budget makes any stall a fast absmax
// failure instead of a hang.
__global__ __launch_bounds__(256, 1) void k_scan(
    const float* __restrict__ Whh, const __hip_bfloat16* __restrict__ xg,
    const float* __restrict__ state_in, __hip_bfloat16* __restrict__ h_all,
    float* __restrict__ out_hs, float* __restrict__ out_hn, float* __restrict__ out_cn) {
  __shared__ __hip_bfloat16 Wl[32 * 2048];   // fragment-major W slice (128 KB)
  __shared__ float gl[64 * 68];              // 64 batches x 64 gate cols (+4 pad)
  const int tid = threadIdx.x;
  const int wg = blockIdx.x;
  const int u0 = wg * UPW;
  // W_hh slice -> LDS bf16 fragment-major (once; reused for all 128 steps)
  // row j = gate*16 + uu; chunk kq = ko>>5 holds 64 rows x 32 k-units.
  for (int e = tid; e < 64 * 128; e += 256) {
    int j = e >> 7;
    int ko = (e & 127) << 3;
    int gate = j >> 4, uu = j & 15;
    const float* src = Whh + (size_t)(gate * HID + u0 + uu) * HID + ko;
    float4 f0 = *(const float4*)(src);
    float4 f1 = *(const float4*)(src + 4);
    union { bf16x8 v; short s[8]; } o;
    o.s[0]=f2bf_s(f0.x); o.s[1]=f2bf_s(f0.y); o.s[2]=f2bf_s(f0.z); o.s[3]=f2bf_s(f0.w);
    o.s[4]=f2bf_s(f1.x); o.s[5]=f2bf_s(f1.y); o.s[6]=f2bf_s(f1.z); o.s[7]=f2bf_s(f1.w);
    *(bf16x8*)(&Wl[(ko >> 5) * 2048 + j * 32 + ((ko >> 3) & 3) * 8]) = o.v;
  }
  const int b = tid >> 2, x = tid & 3;       // thread: batch b, units x*4..x*4+3
  f32x4 c4i = *(const f32x4*)(state_in + (size_t)b * HID + u0 + x * 4);
  float cc[4] = {c4i[0], c4i[1], c4i[2], c4i[3]};
  const int w = tid >> 6, lane = tid & 63;
  const int lm = lane & 15, quad = lane >> 4;
  const int m0 = w * 16;                     // wave's batch tile
  union U64 { unsigned long long u; unsigned short s[4]; };
  U64 xv[4];
  {
    const unsigned short* xp = (const unsigned short*)xg + (size_t)b * GATES + u0 + x * 4;
#pragma unroll
    for (int g = 0; g < 4; ++g) xv[g].u = *(const unsigned long long*)(xp + g * 1024);
  }
  int budget = 1 << 20;                      // global spin budget (hang-proof)
  __syncthreads();
  for (int t = 0; t < L_SEQ; ++t) {
    // per-lane base into slot t (chunk-16 layout): fragment for MFMA chunk kq
    // = 16 B at [c = kq*2 + (quad>>1)][b = m0+lm][u' = (quad&1)*8]
    const char* a0 = (const char*)h_all + (size_t)t * SLOTB
                   + (size_t)(quad >> 1) * 2048 + (size_t)(m0 + lm) * 32
                   + (size_t)(quad & 1) * 16;
    union BF8 { bf16x8 v; unsigned long long q[2]; } areg[32];
#pragma unroll
    for (int kq = 0; kq < 32; ++kq) {
      areg[kq].q[0] = __hip_atomic_load(
          (const unsigned long long*)(a0 + (size_t)kq * 4096),
          __ATOMIC_RELAXED, __HIP_MEMORY_SCOPE_SYSTEM);
      areg[kq].q[1] = __hip_atomic_load(
          (const unsigned long long*)(a0 + (size_t)kq * 4096 + 8),
          __ATOMIC_RELAXED, __HIP_MEMORY_SCOPE_SYSTEM);
    }
    __builtin_amdgcn_sched_barrier(0);       // keep the load batch above MFMAs
    f32x4 acc[4] = {{0.f,0.f,0.f,0.f}, {0.f,0.f,0.f,0.f},
                    {0.f,0.f,0.f,0.f}, {0.f,0.f,0.f,0.f}};
#pragma unroll
    for (int kq = 0; kq < 32; ++kq) {
      if (t > 0) {                           // slot 0 is pre-written, race-free
        while (__any(is_can(areg[kq].q[0]) || is_can(areg[kq].q[1]))) {
          if (--budget < 0) break;           // hang-proof: fail fast, not dead
          __builtin_amdgcn_s_sleep(1);
          areg[kq].q[0] = __hip_atomic_load(
              (const unsigned long long*)(a0 + (size_t)kq * 4096),
              __ATOMIC_RELAXED, __HIP_MEMORY_SCOPE_SYSTEM);
          areg[kq].q[1] = __hip_atomic_load(
              (const unsigned long long*)(a0 + (size_t)kq * 4096 + 8),
              __ATOMIC_RELAXED, __HIP_MEMORY_SCOPE_SYSTEM);
        }
      }
#pragma unroll
      for (int n = 0; n < 4; ++n) {
        bf16x8 bfrag = *(const bf16x8*)(&Wl[kq * 2048 + (n * 16 + lm) * 32 + quad * 8]);
        acc[n] = __builtin_amdgcn_mfma_f32_16x16x32_bf16(areg[kq].v, bfrag, acc[n], 0, 0, 0);
      }
    }
    // C/D layout: col = lane&15, row = quad*4 + reg
#pragma unroll
    for (int n = 0; n < 4; ++n)
#pragma unroll
      for (int r = 0; r < 4; ++r)
        gl[(m0 + quad * 4 + r) * 68 + n * 16 + lm] = acc[n][r];
    __syncthreads();
    f32x4 gi4 = *(const f32x4*)(&gl[b * 68 + 0  + x * 4]);
    f32x4 gf4 = *(const f32x4*)(&gl[b * 68 + 16 + x * 4]);
    f32x4 gg4 = *(const f32x4*)(&gl[b * 68 + 32 + x * 4]);
    f32x4 go4 = *(const f32x4*)(&gl[b * 68 + 48 + x * 4]);
    float hv[4];
    U64 hp;
#pragma unroll
    for (int j = 0; j < 4; ++j) {
      float ii = sigm(gi4[j] + bf2f_u(xv[0].s[j]));
      float ff = sigm(gf4[j] + bf2f_u(xv[1].s[j]));
      float gv = tanh_f(gg4[j] + bf2f_u(xv[2].s[j]));
      float oo = sigm(go4[j] + bf2f_u(xv[3].s[j]));
      cc[j] = ff * cc[j] + ii * gv;
      hv[j] = oo * tanh_f(cc[j]);
      hp.s[j] = (unsigned short)f2bf_s(hv[j]);
    }
    f32x4 hv4 = {hv[0], hv[1], hv[2], hv[3]};
    float* hsout = out_hs + ((size_t)t * BATCH + b) * HID + u0 + x * 4;
    if (t == L_SEQ - 1) {
      __builtin_nontemporal_store(hv4, (f32x4*)hsout);
      f32x4 cc4 = {cc[0], cc[1], cc[2], cc[3]};
      __builtin_nontemporal_store(hv4, (f32x4*)(out_hn + (size_t)b * HID + u0 + x * 4));
      __builtin_nontemporal_store(cc4, (f32x4*)(out_cn + (size_t)b * HID + u0 + x * 4));
    } else {
      // publish h: each thread stores its OWN u64 (4 contiguous units) to its
      // WG's 2 KB chunk of slot t+1. No waitcnt, no flag, no barrier — the
      // per-4B canary check on the consumer side IS the synchronization.
      unsigned long long* hdst = (unsigned long long*)
          ((char*)h_all + (size_t)(t + 1) * SLOTB + (size_t)wg * 2048 + (size_t)b * 32);
      __hip_atomic_store(&hdst[x], hp.u, __ATOMIC_RELAXED, __HIP_MEMORY_SCOPE_SYSTEM);
      // overlap with neighbors' publishing: hs output + xg prefetch for t+1
      __builtin_nontemporal_store(hv4, (f32x4*)hsout);
      {
        const unsigned short* xp = (const unsigned short*)xg +
            ((size_t)(t + 1) * BATCH + b) * GATES + u0 + x * 4;
#pragma unroll
        for (int g = 0; g < 4; ++g) xv[g].u = *(const unsigned long long*)(xp + g * 1024);
      }
      __syncthreads();                       // gl reuse guard only (intra-WG)
    }
  }
}

extern "C" void kernel_launch(void* const* d_in, const int* in_sizes, int n_in,
                              void* d_out, int out_size, void* d_ws, size_t ws_size,
                              hipStream_t stream) {
  const float* x      = (const float*)d_in[0];
  const int*   pa     = (const int*)d_in[1];
  // d_in[2] = mask (unused by reference)
  const float* hidden = (const float*)d_in[3];
  const float* state  = (const float*)d_in[4];
  const float* remb   = (const float*)d_in[5];
  const float* temb   = (const float*)d_in[6];
  const float* Wih    = (const float*)d_in[7];
  const float* Whh    = (const float*)d_in[8];
  const float* bih    = (const float*)d_in[9];
  const float* bhh    = (const float*)d_in[10];

  char* ws = (char*)d_ws;
  size_t off = 0;
  auto take = [&](size_t bytes) { char* p = ws + off; off += (bytes + 255) & ~(size_t)255; return p; };
  __hip_bfloat16* h_all = (__hip_bfloat16*)take((size_t)(L_SEQ + 1) * BATCH * HID * 2); // chunked slots
  __hip_bfloat16* x_bf  = (__hip_bfloat16*)take((size_t)BATCH * 512 * 2);
  float* bias2          = (float*)take((size_t)GATES * 4);
  __hip_bfloat16* Wx    = (__hip_bfloat16*)take((size_t)GATES * 512 * 2);
  __hip_bfloat16* Wa    = (__hip_bfloat16*)take((size_t)GATES * 512 * 2);
  __hip_bfloat16* act   = (__hip_bfloat16*)take((size_t)8192 * 512 * 2);
  float* y0             = (float*)take((size_t)BATCH * GATES * 4);
  __hip_bfloat16* xg    = (__hip_bfloat16*)take((size_t)8192 * GATES * 2); // ~97 MB total

  float* out_hs = (float*)d_out;
  float* out_hn = out_hs + (size_t)L_SEQ * BATCH * HID;
  float* out_cn = out_hn + (size_t)BATCH * HID;

  hipLaunchKernelGGL(k_init, dim3(256), dim3(256), 0, stream, hidden, x, bih, bhh, h_all, x_bf, bias2);
  hipLaunchKernelGGL(k_wsplit, dim3(2048), dim3(256), 0, stream, Wih, Wx, Wa);
  hipLaunchKernelGGL(k_act, dim3(8192), dim3(64), 0, stream, pa, remb, temb, act);
  hipLaunchKernelGGL((k_gemm<0>), dim3(32, 1), dim3(256), 0, stream,
                     x_bf, Wx, bias2, y0, (__hip_bfloat16*)nullptr, 64);
  hipLaunchKernelGGL((k_gemm<1>), dim3(32, 64), dim3(256), 0, stream,
                     act, Wa, y0, (float*)nullptr, xg, 8192);
  // REGULAR launch (the one change vs v11): canary protocol needs no
  // grid.sync; 64 blocks <= 256 CUs are co-resident on an idle device.
  hipLaunchKernelGGL(k_scan, dim3(NWG), dim3(256), 0, stream,
                     Whh, xg, state, h_all, out_hs, out_hn, out_cn);
}